// Round 5
// baseline (59.931 us; speedup 1.0000x reference)
//
#include <hip/hip_runtime.h>

#define NDIM   16
#define MCOLS  2048
#define NANG   120           // 16*15/2
#define BLOCK  256
#define COLS_PER_WG 1024

typedef float f32x4 __attribute__((ext_vector_type(4)));

// ---------- Kernel 1: one 64-thread wave per block computes mus-scaled R into ws.
__global__ __launch_bounds__(64) void build_R_kernel(
    const float* __restrict__ angles,
    const float* __restrict__ mus,
    float* __restrict__ Rws)
{
    const int b    = blockIdx.x;
    const int lane = threadIdx.x;
    __shared__ float c_lds[NANG];
    __shared__ float s_lds[NANG];

#pragma unroll
    for (int rep = 0; rep < 2; ++rep) {
        const int k = lane + rep * 64;
        if (k < NANG) {
            float sv, cv;
            sincosf(angles[b * NANG + k], &sv, &cv);
            c_lds[k] = cv;
            s_lds[k] = sv;
        }
    }
    __syncthreads();

    if (lane < NDIM) {
        const int j = lane;
        float m[NDIM];
#pragma unroll
        for (int r = 0; r < NDIM; ++r) m[r] = (r == j) ? 1.0f : 0.0f;
        int k = 0;
#pragma unroll
        for (int iTop = 0; iTop < NDIM - 1; ++iTop) {
            float vt = m[iTop];
#pragma unroll
            for (int iBtm = iTop + 1; iBtm < NDIM; ++iBtm) {
                const float c  = c_lds[k];
                const float s  = s_lds[k];
                const float vb = m[iBtm];
                const float nvt = c * vt - s * vb;
                m[iBtm] = s * vt + c * vb;
                vt = nvt;
                ++k;
            }
            m[iTop] = vt;
        }
#pragma unroll
        for (int r = 0; r < NDIM; ++r)
            Rws[b * (NDIM * NDIM) + r * NDIM + j] = mus[b * NDIM + r] * m[r];
    }
}

// ---------- Kernel 2: pure streaming out = R @ X, one WG per block, 2 chunks.
__global__ __launch_bounds__(BLOCK) void apply_kernel(
    const float* __restrict__ X,
    const float* __restrict__ Rws,
    float* __restrict__ out)
{
    const int b   = blockIdx.x;
    const int tid = threadIdx.x;
    __shared__ __align__(16) float R_lds[NDIM * NDIM];

    if (tid < 64)
        *reinterpret_cast<f32x4*>(&R_lds[tid * 4]) =
            *reinterpret_cast<const f32x4*>(&Rws[b * (NDIM * NDIM) + tid * 4]);
    __syncthreads();

    const float* Xb = X   + (size_t)b * NDIM * MCOLS;
    float*       Ob = out + (size_t)b * NDIM * MCOLS;

#pragma unroll
    for (int chunk = 0; chunk < 2; ++chunk) {
        const int col = chunk * COLS_PER_WG + tid * 4;
        f32x4 x4[NDIM];
#pragma unroll
        for (int jj = 0; jj < NDIM; ++jj)
            x4[jj] = *reinterpret_cast<const f32x4*>(Xb + jj * MCOLS + col);

#pragma unroll
        for (int r = 0; r < NDIM; ++r) {
            f32x4 acc = (f32x4)(0.f);
#pragma unroll
            for (int q = 0; q < NDIM; ++q)
                acc += R_lds[r * NDIM + q] * x4[q];
            __builtin_nontemporal_store(acc, reinterpret_cast<f32x4*>(Ob + r * MCOLS + col));
        }
    }
}

// ---------- Fallback fused kernel (used only if ws is too small).
__global__ __launch_bounds__(BLOCK) void soot_fused_kernel(
    const float* __restrict__ X,
    const float* __restrict__ angles,
    const float* __restrict__ mus,
    float* __restrict__ out)
{
    __shared__ float c_lds[NANG];
    __shared__ float s_lds[NANG];
    __shared__ __align__(16) float R_lds[NDIM * NDIM];

    const int wg   = blockIdx.x;
    const int b    = wg >> 1;
    const int half = wg & 1;
    const int tid  = threadIdx.x;

    if (tid < 64) {
#pragma unroll
        for (int rep = 0; rep < 2; ++rep) {
            const int k = tid + rep * 64;
            if (k < NANG) {
                float a = angles[b * NANG + k];
                float sv, cv;
                sincosf(a, &sv, &cv);
                c_lds[k] = cv;
                s_lds[k] = sv;
            }
        }
    }
    __syncthreads();

    if (tid < NDIM) {
        const int j = tid;
        float m[NDIM];
#pragma unroll
        for (int r = 0; r < NDIM; ++r) m[r] = (r == j) ? 1.0f : 0.0f;
        int k = 0;
#pragma unroll
        for (int iTop = 0; iTop < NDIM - 1; ++iTop) {
            float vt = m[iTop];
#pragma unroll
            for (int iBtm = iTop + 1; iBtm < NDIM; ++iBtm) {
                const float c  = c_lds[k];
                const float s  = s_lds[k];
                const float vb = m[iBtm];
                const float nvt = c * vt - s * vb;
                m[iBtm] = s * vt + c * vb;
                vt = nvt;
                ++k;
            }
            m[iTop] = vt;
        }
#pragma unroll
        for (int r = 0; r < NDIM; ++r)
            R_lds[r * NDIM + j] = mus[b * NDIM + r] * m[r];
    }
    __syncthreads();

    const int col = half * COLS_PER_WG + tid * 4;
    const float* Xb = X   + (size_t)b * NDIM * MCOLS;
    float*       Ob = out + (size_t)b * NDIM * MCOLS;

    f32x4 x4[NDIM];
#pragma unroll
    for (int jj = 0; jj < NDIM; ++jj)
        x4[jj] = *reinterpret_cast<const f32x4*>(Xb + jj * MCOLS + col);

#pragma unroll
    for (int r = 0; r < NDIM; ++r) {
        f32x4 acc = (f32x4)(0.f);
#pragma unroll
        for (int q = 0; q < NDIM; ++q)
            acc += R_lds[r * NDIM + q] * x4[q];
        __builtin_nontemporal_store(acc, reinterpret_cast<f32x4*>(Ob + r * MCOLS + col));
    }
}

extern "C" void kernel_launch(void* const* d_in, const int* in_sizes, int n_in,
                              void* d_out, int out_size, void* d_ws, size_t ws_size,
                              hipStream_t stream) {
    const float* X      = (const float*)d_in[0];
    const float* angles = (const float*)d_in[1];
    const float* mus    = (const float*)d_in[2];
    float* out          = (float*)d_out;

    const int nblks = in_sizes[1] / NANG;          // 1024
    const size_t ws_needed = (size_t)nblks * NDIM * NDIM * sizeof(float);

    if (ws_size >= ws_needed) {
        float* Rws = (float*)d_ws;
        hipLaunchKernelGGL(build_R_kernel, dim3(nblks), dim3(64), 0, stream,
                           angles, mus, Rws);
        hipLaunchKernelGGL(apply_kernel, dim3(nblks), dim3(BLOCK), 0, stream,
                           X, Rws, out);
    } else {
        hipLaunchKernelGGL(soot_fused_kernel,
                           dim3(nblks * (MCOLS / COLS_PER_WG)), dim3(BLOCK), 0, stream,
                           X, angles, mus, out);
    }
}

// Round 6
// 46.107 us; speedup vs baseline: 1.2998x; 1.2998x over previous
//
#include <hip/hip_runtime.h>

#define NDIM   16
#define MCOLS  2048
#define NANG   120           // 16*15/2
#define BLOCK  256
#define COLS_PER_WG 1024     // 256 threads * 4 cols (float4)

typedef float f32x4 __attribute__((ext_vector_type(4)));

__global__ __launch_bounds__(BLOCK) void soot_kernel(
    const float* __restrict__ X,
    const float* __restrict__ angles,
    const float* __restrict__ mus,
    float* __restrict__ out)
{
    __shared__ float c_lds[NANG];
    __shared__ float s_lds[NANG];
    __shared__ __align__(16) float R_lds[NDIM * NDIM];

    const int wg   = blockIdx.x;
    const int b    = wg >> 1;      // block index
    const int half = wg & 1;       // which half of the 2048 columns
    const int tid  = threadIdx.x;

    // Stage 1: wave 0 computes cos/sin of the 120 angles into LDS (2 per lane).
    if (tid < 64) {
#pragma unroll
        for (int rep = 0; rep < 2; ++rep) {
            const int k = tid + rep * 64;
            if (k < NANG) {
                float a = angles[b * NANG + k];
                float sv, cv;
                sincosf(a, &sv, &cv);
                c_lds[k] = cv;
                s_lds[k] = sv;
            }
        }
    }
    __syncthreads();

    // Stage 2: 16 threads (thread j owns column j of M) run the Givens cascade.
    if (tid < NDIM) {
        const int j = tid;
        float m[NDIM];
#pragma unroll
        for (int r = 0; r < NDIM; ++r) m[r] = (r == j) ? 1.0f : 0.0f;
        int k = 0;
#pragma unroll
        for (int iTop = 0; iTop < NDIM - 1; ++iTop) {
            float vt = m[iTop];
#pragma unroll
            for (int iBtm = iTop + 1; iBtm < NDIM; ++iBtm) {
                const float c  = c_lds[k];
                const float s  = s_lds[k];
                const float vb = m[iBtm];
                const float nvt = c * vt - s * vb;
                m[iBtm] = s * vt + c * vb;
                vt = nvt;
                ++k;
            }
            m[iTop] = vt;
        }
        // Row-scale by mus and write R (row-major) to LDS.
#pragma unroll
        for (int r = 0; r < NDIM; ++r)
            R_lds[r * NDIM + j] = mus[b * NDIM + r] * m[r];
    }
    __syncthreads();

    // Stage 3: out = R @ X, two K-phases so peak live regs stay ~96:
    //   phase 0: x rows 0..7  -> acc[16] (init)
    //   phase 1: x rows 8..15 -> acc[16] (finish), reusing the same 8 x-regs.
    // Every X byte is loaded by exactly one dwordx4 (no L1/L2 re-reads).
    const int col = half * COLS_PER_WG + tid * 4;
    const float* Xb = X   + (size_t)b * NDIM * MCOLS;
    float*       Ob = out + (size_t)b * NDIM * MCOLS;

    f32x4 x[8];
    f32x4 acc[NDIM];

    // Phase 0: rows 0..7
#pragma unroll
    for (int j = 0; j < 8; ++j)
        x[j] = *reinterpret_cast<const f32x4*>(Xb + j * MCOLS + col);
#pragma unroll
    for (int r = 0; r < NDIM; ++r) {
        acc[r] = R_lds[r * NDIM + 0] * x[0];
#pragma unroll
        for (int q = 1; q < 8; ++q)
            acc[r] += R_lds[r * NDIM + q] * x[q];
    }

    // Phase 1: rows 8..15 (reuse x[])
#pragma unroll
    for (int j = 0; j < 8; ++j)
        x[j] = *reinterpret_cast<const f32x4*>(Xb + (8 + j) * MCOLS + col);
#pragma unroll
    for (int r = 0; r < NDIM; ++r) {
#pragma unroll
        for (int q = 0; q < 8; ++q)
            acc[r] += R_lds[r * NDIM + 8 + q] * x[q];
    }

    // Store (write-once output: nontemporal).
#pragma unroll
    for (int r = 0; r < NDIM; ++r)
        __builtin_nontemporal_store(acc[r], reinterpret_cast<f32x4*>(Ob + r * MCOLS + col));
}

extern "C" void kernel_launch(void* const* d_in, const int* in_sizes, int n_in,
                              void* d_out, int out_size, void* d_ws, size_t ws_size,
                              hipStream_t stream) {
    const float* X      = (const float*)d_in[0];
    const float* angles = (const float*)d_in[1];
    const float* mus    = (const float*)d_in[2];
    float* out          = (float*)d_out;

    const int nblks = in_sizes[1] / NANG;          // 1024
    dim3 grid(nblks * (MCOLS / COLS_PER_WG));      // 2 workgroups per block
    dim3 block(BLOCK);
    hipLaunchKernelGGL(soot_kernel, grid, block, 0, stream,
                       X, angles, mus, out);
}